// Round 3
// baseline (306.961 us; speedup 1.0000x reference)
//
#include <hip/hip_runtime.h>

#define BN 1024      // B
#define EN 50000     // E
#define CN 512       // CLASS_NUM
#define JT 64        // tail rows per block in the fused kernel

typedef float v4f __attribute__((ext_vector_type(4)));

// ---------------------------------------------------------------------------
// Kernel 1 (tiny): hr_parts[i] = dot(hr[i,:], W1) + b, one wave per row.
// 256 blocks x 256 threads = 1024 waves exactly. ~3 µs.
// Also writes the trailing scalar tuple element.
// ---------------------------------------------------------------------------
__global__ __launch_bounds__(256) void hr_kernel(
    const float* __restrict__ hr,
    const float* __restrict__ W,
    const float* __restrict__ bptr,
    float* __restrict__ hr_parts,
    float* __restrict__ out)
{
    const int gtid = blockIdx.x * blockDim.x + threadIdx.x;
    const int wave = gtid >> 6;          // 0..1023 == hr row
    const int lane = threadIdx.x & 63;

    const v4f* r4 = (const v4f*)(hr + (size_t)wave * CN);
    const v4f* w4 = (const v4f*)W;       // W1 = W[0, 0:512]

    v4f p = r4[lane] * w4[lane] + r4[lane + 64] * w4[lane + 64];
    float sum = p.x + p.y + p.z + p.w;

    #pragma unroll
    for (int off = 32; off > 0; off >>= 1)
        sum += __shfl_down(sum, off, 64);

    if (lane == 0) hr_parts[wave] = sum + bptr[0];
    if (gtid == 0) out[(size_t)BN * EN] = 0.0f;
}

// ---------------------------------------------------------------------------
// Kernel 2 (fused): per block of 64 tail rows [j0, j0+64):
//   phase 1: 4 waves x 16 rows -> tail dots vs W2 -> LDS tails[64]
//   phase 2: write out[i][j0:j0+64] for ALL i in [0,1024):
//     16 thread-groups of 16; group g owns rows g*64..g*64+63; thread c in
//     the group owns v4f column c. Group store = 256 B contiguous; hv load
//     is group-uniform (broadcast); tj is loop-invariant (hoisted register).
// tail_parts never touch HBM; tail is read once; out written once.
// grid = ceil(50000/64) = 782 blocks (~3/CU), 256 threads.
// ---------------------------------------------------------------------------
__global__ __launch_bounds__(256) void fused_kernel(
    const float* __restrict__ tail,
    const float* __restrict__ W,
    const float* __restrict__ hr_parts,
    float* __restrict__ out)
{
    __shared__ float tails[JT];

    const int j0   = blockIdx.x * JT;
    const int w    = threadIdx.x >> 6;   // wave 0..3
    const int lane = threadIdx.x & 63;

    const v4f* w4 = (const v4f*)(W + CN);    // W2 = W[0, 512:1024]
    const v4f wb0 = w4[lane];
    const v4f wb1 = w4[lane + 64];

    // --- phase 1: 16 row-dots per wave ---
    #pragma unroll 4
    for (int r = 0; r < 16; ++r) {
        const int j = j0 + w * 16 + r;
        if (j < EN) {
            const v4f* r4 = (const v4f*)(tail + (size_t)j * CN);
            v4f p = r4[lane] * wb0 + r4[lane + 64] * wb1;
            float sum = p.x + p.y + p.z + p.w;
            #pragma unroll
            for (int off = 32; off > 0; off >>= 1)
                sum += __shfl_down(sum, off, 64);
            if (lane == 0) tails[w * 16 + r] = sum;
        }
    }
    __syncthreads();

    // --- phase 2: broadcast-write the 1024 x 64 output tile ---
    const int g = threadIdx.x >> 4;      // row-group 0..15
    const int c = threadIdx.x & 15;      // v4f column within tile
    const int j = j0 + c * 4;
    if (j < EN) {                        // tail remainder (16) is v4f-aligned
        const v4f tj = *(const v4f*)&tails[c * 4];
        float* obase = out + (size_t)g * 64 * EN + j;
        #pragma unroll 4
        for (int p = 0; p < 64; ++p) {
            const float hv = hr_parts[g * 64 + p];   // group-uniform, L1-hot
            v4f o = tj + hv;
            *(v4f*)(obase + (size_t)p * EN) = o;
        }
    }
}

extern "C" void kernel_launch(void* const* d_in, const int* in_sizes, int n_in,
                              void* d_out, int out_size, void* d_ws, size_t ws_size,
                              hipStream_t stream)
{
    const float* hr   = (const float*)d_in[0];   // (1024, 512)
    const float* tail = (const float*)d_in[1];   // (50000, 512)
    const float* W    = (const float*)d_in[2];   // (1, 1024)
    const float* b    = (const float*)d_in[3];   // (1,)
    float* out = (float*)d_out;
    float* hr_parts = (float*)d_ws;              // 1024 floats

    hr_kernel<<<256, 256, 0, stream>>>(hr, W, b, hr_parts, out);

    const int blocks = (EN + JT - 1) / JT;       // 782
    fused_kernel<<<blocks, 256, 0, stream>>>(tail, W, hr_parts, out);
}